// Round 5
// baseline (374.868 us; speedup 1.0000x reference)
//
#include <hip/hip_runtime.h>
#include <hip/hip_bf16.h>

#define N_NODES 100000
#define N_EDGES 800000
#define D 128
#define NG 64
#define SCAN_NB ((N_NODES + 255) / 256)   // 391
#define NTILES ((N_NODES + 63) / 64)      // 1563

typedef __attribute__((ext_vector_type(8))) short short8;
typedef __attribute__((ext_vector_type(4))) float f32x4;
typedef __attribute__((ext_vector_type(2))) float f32x2;

static __device__ __forceinline__ unsigned short f2bf(float f) {
    unsigned u = __float_as_uint(f);
    unsigned r = (u + 0x7FFF + ((u >> 16) & 1)) >> 16;   // RTN-even
    return (unsigned short)r;
}
static __device__ __forceinline__ float bf2f(unsigned short b) {
    return __uint_as_float((unsigned)b << 16);
}
static __device__ __forceinline__ unsigned char f2fp8(float v) {
    int p = __builtin_amdgcn_cvt_pk_fp8_f32(v, v, 0, false);  // RNE, OCP e4m3fn
    return (unsigned char)(p & 0xFF);
}
static __device__ __forceinline__ f32x2 fp8x2_f32(unsigned short s) {
    return __builtin_amdgcn_cvt_pk_f32_fp8((int)s, false);
}

// ---------------- CSR build: histogram / scan(+dinv) / fill ----------------

__global__ void hist_kernel(const int* __restrict__ dst, int* __restrict__ deg) {
    int e = blockIdx.x * blockDim.x + threadIdx.x;
    if (e < N_EDGES) atomicAdd(&deg[dst[e]], 1);
}

__global__ __launch_bounds__(256) void scan1_kernel(const int* __restrict__ deg,
                                                    int* __restrict__ rs,
                                                    int* __restrict__ bsum,
                                                    float* __restrict__ dinv) {
    __shared__ int wsum[4];
    int i = blockIdx.x * 256 + threadIdx.x;
    int lane = threadIdx.x & 63;
    int wid = threadIdx.x >> 6;
    int v = (i < N_NODES) ? deg[i] : 0;
    if (i < N_NODES) dinv[i] = rsqrtf((float)v + 1.0f);  // +1 self loop
    int x = v;
    #pragma unroll
    for (int off = 1; off < 64; off <<= 1) {
        int y = __shfl_up(x, off);
        if (lane >= off) x += y;
    }
    if (lane == 63) wsum[wid] = x;
    __syncthreads();
    int add = 0;
    #pragma unroll
    for (int w = 0; w < 3; ++w) if (w < wid) add += wsum[w];
    int incl = x + add;
    if (i < N_NODES) rs[i] = incl - v;
    if (threadIdx.x == 255) bsum[blockIdx.x] = incl;
}

__global__ __launch_bounds__(512) void scan2_kernel(int* __restrict__ bsum) {
    __shared__ int s[512];
    int t = threadIdx.x;
    int v = (t < SCAN_NB) ? bsum[t] : 0;
    s[t] = v;
    __syncthreads();
    for (int off = 1; off < 512; off <<= 1) {
        int y = (t >= off) ? s[t - off] : 0;
        __syncthreads();
        s[t] += y;
        __syncthreads();
    }
    if (t < SCAN_NB) bsum[t] = s[t] - v;
}

__global__ void scan3_kernel(int* __restrict__ rs, const int* __restrict__ bsum) {
    int i = blockIdx.x * blockDim.x + threadIdx.x;
    if (i < N_NODES) rs[i] += bsum[i >> 8];
    if (i == 0) rs[N_NODES] = N_EDGES;
}

__global__ void fill_kernel(const int* __restrict__ src, const int* __restrict__ dst,
                            const float* __restrict__ dinv, const int* __restrict__ rs,
                            int* __restrict__ cursor, int2* __restrict__ pairs) {
    int e = blockIdx.x * blockDim.x + threadIdx.x;
    if (e < N_EDGES) {
        int d = dst[e];
        int s = src[e];
        int p = rs[d] + atomicAdd(&cursor[d], 1);
        pairs[p] = make_int2(s, __float_as_int(dinv[s] * dinv[d]));
    }
}

// ---------------- graph boundaries from sorted batch ----------------

__global__ void bounds_kernel(const int* __restrict__ batch, int* __restrict__ start) {
    int g = threadIdx.x;
    if (g > NG) return;
    if (g == NG) { start[NG] = N_NODES; return; }
    int lo = 0, hi = N_NODES;
    while (lo < hi) {
        int mid = (lo + hi) >> 1;
        if (batch[mid] < g) lo = mid + 1; else hi = mid;
    }
    start[g] = lo;
}

// ---------------- dense transform via MFMA: Hq = fp8( A @ (Whi+Wlo) ) ------
// block = 512 thr = 8 waves (4M x 2N), tile = 64 nodes x 128 feats.
// W hi/lo transposed+swizzled in LDS once per block; A tile per iter.

template <bool IN_F32>
__global__ __launch_bounds__(512) void xw_mfma_kernel(const void* __restrict__ Xin,
                                                      const float* __restrict__ W,
                                                      unsigned char* __restrict__ Hq) {
    __shared__ __align__(16) unsigned short bt_hi[128 * 128];  // 32 KB, Bt[n][k]
    __shared__ __align__(16) unsigned short bt_lo[128 * 128];  // 32 KB
    __shared__ __align__(16) unsigned short atile[64 * 128];   // 16 KB, A[row][k]

    const int t = threadIdx.x;
    const int lane = t & 63;
    const int wid = t >> 6;

    #pragma unroll 4
    for (int i = 0; i < 32; ++i) {
        int idx = t + i * 512;
        int k = idx >> 7;
        int n = idx & 127;
        float w = W[idx];
        unsigned short hi = f2bf(w);
        unsigned short lo = f2bf(w - bf2f(hi));
        int byte = (n * 256 + k * 2) ^ ((n & 7) << 4);
        *(unsigned short*)((char*)bt_hi + byte) = hi;
        *(unsigned short*)((char*)bt_lo + byte) = lo;
    }

    const int mrow = (wid >> 1) * 16;
    const int ncol = (wid & 1) * 64;
    const int ar = mrow + (lane & 15);
    const int ak = (lane >> 4) * 8;

    for (int tile = blockIdx.x; tile < NTILES; tile += gridDim.x) {
        const int node0 = tile * 64;
        __syncthreads();

        #pragma unroll
        for (int p = 0; p < 2; ++p) {
            int j = t + p * 512;
            int row = j >> 4;
            int c8 = (j & 15) * 8;
            int node = node0 + row;
            short8 v = 0;
            if (IN_F32) {
                const float* X = (const float*)Xin;
                if (node < N_NODES) {
                    const float* xr = &X[(size_t)node * 128 + c8];
                    float4 a = *(const float4*)xr;
                    float4 b = *(const float4*)(xr + 4);
                    v[0] = (short)f2bf(a.x); v[1] = (short)f2bf(a.y);
                    v[2] = (short)f2bf(a.z); v[3] = (short)f2bf(a.w);
                    v[4] = (short)f2bf(b.x); v[5] = (short)f2bf(b.y);
                    v[6] = (short)f2bf(b.z); v[7] = (short)f2bf(b.w);
                }
            } else {
                const unsigned short* X = (const unsigned short*)Xin;
                if (node < N_NODES) v = *(const short8*)&X[(size_t)node * 128 + c8];
            }
            int byte = (row * 256 + c8 * 2) ^ ((row & 7) << 4);
            *(short8*)((char*)atile + byte) = v;
        }
        __syncthreads();

        f32x4 acc[4];
        #pragma unroll
        for (int nt = 0; nt < 4; ++nt) acc[nt] = 0.f;

        #pragma unroll
        for (int kc = 0; kc < 128; kc += 32) {
            short8 a = *(const short8*)((const char*)atile +
                        ((ar * 256 + (kc + ak) * 2) ^ ((ar & 7) << 4)));
            #pragma unroll
            for (int nt = 0; nt < 4; ++nt) {
                int col = ncol + nt * 16 + (lane & 15);
                int boff = (col * 256 + (kc + ak) * 2) ^ ((col & 7) << 4);
                short8 bh = *(const short8*)((const char*)bt_hi + boff);
                acc[nt] = __builtin_amdgcn_mfma_f32_16x16x32_bf16(a, bh, acc[nt], 0, 0, 0);
                short8 bl = *(const short8*)((const char*)bt_lo + boff);
                acc[nt] = __builtin_amdgcn_mfma_f32_16x16x32_bf16(a, bl, acc[nt], 0, 0, 0);
            }
        }

        // ---- store C as fp8 (byte stores) ----
        #pragma unroll
        for (int nt = 0; nt < 4; ++nt) {
            #pragma unroll
            for (int r = 0; r < 4; ++r) {
                int node = node0 + mrow + (lane >> 4) * 4 + r;
                if (node < N_NODES)
                    Hq[(size_t)node * 128 + ncol + nt * 16 + (lane & 15)] = f2fp8(acc[nt][r]);
            }
        }
    }
}

// ---------------- CSR gather (fp8 in, bf16 out) + fused epilogue -----------
// wave per node, lane covers feats 2f,2f+1 (2 fp8 = ushort load).
// predicated unroll-8: clamped index, zero weight for tail -> no serial tail.

__global__ __launch_bounds__(256) void gather_kernel(const unsigned char* __restrict__ Hq,
                                                     const int* __restrict__ rs,
                                                     const int2* __restrict__ pairs,
                                                     const float* __restrict__ dinv,
                                                     const float* __restrict__ bias,
                                                     unsigned short* __restrict__ out) {
    int node = blockIdx.x * 4 + (threadIdx.x >> 6);
    if (node >= N_NODES) return;
    int lane = threadIdx.x & 63;

    float di = dinv[node];
    unsigned short sv = *(const unsigned short*)&Hq[(size_t)node * 128 + lane * 2];
    f32x2 hs = fp8x2_f32(sv);
    float2 bb = *(const float2*)&bias[lane * 2];
    float ax = hs[0] * di * di + bb.x;
    float ay = hs[1] * di * di + bb.y;

    int beg = rs[node];
    int end = rs[node + 1];
    if (end > beg) {
        int last = end - 1;
        for (int i = beg; i < end; i += 8) {
            #pragma unroll
            for (int j = 0; j < 8; ++j) {
                int idx = i + j;
                int2 p = pairs[min(idx, last)];
                float w = (idx < end) ? __int_as_float(p.y) : 0.f;
                unsigned short hv = *(const unsigned short*)&Hq[(size_t)p.x * 128 + lane * 2];
                f32x2 hf = fp8x2_f32(hv);
                ax = fmaf(hf[0], w, ax);
                ay = fmaf(hf[1], w, ay);
            }
        }
    }
    ushort2 o;
    o.x = f2bf(fmaxf(ax, 0.f));
    o.y = f2bf(fmaxf(ay, 0.f));
    *(ushort2*)&out[(size_t)node * 128 + lane * 2] = o;
}

// ---------------- mean pool: dense segmented sum over start[] --------------

__global__ __launch_bounds__(256) void pool_kernel(const unsigned short* __restrict__ G,
                                                   const int* __restrict__ start,
                                                   float* __restrict__ sums) {
    __shared__ float red[16][132];
    int g = blockIdx.x >> 4;
    int s = blockIdx.x & 15;
    int n0 = start[g], n1 = start[g + 1];
    int slot = threadIdx.x & 15;
    int nl = threadIdx.x >> 4;

    float acc[8];
    #pragma unroll
    for (int j = 0; j < 8; ++j) acc[j] = 0.f;

    for (int node = n0 + s * 16 + nl; node < n1; node += 256) {
        short8 v = *(const short8*)&G[(size_t)node * 128 + slot * 8];
        #pragma unroll
        for (int j = 0; j < 8; ++j) acc[j] += bf2f((unsigned short)v[j]);
    }

    #pragma unroll
    for (int j = 0; j < 8; ++j) red[nl][slot * 8 + j] = acc[j];
    __syncthreads();
    #pragma unroll
    for (int off = 8; off > 0; off >>= 1) {
        if (nl < off) {
            #pragma unroll
            for (int j = 0; j < 8; ++j)
                red[nl][slot * 8 + j] += red[nl + off][slot * 8 + j];
        }
        __syncthreads();
    }
    if (nl == 0) {
        #pragma unroll
        for (int j = 0; j < 8; ++j)
            unsafeAtomicAdd(&sums[g * D + slot * 8 + j], red[0][slot * 8 + j]);
    }
}

// ---------------- final FC ----------------

__global__ void fc_kernel(const float* __restrict__ sums, const int* __restrict__ start,
                          const float* __restrict__ Wfc, const float* __restrict__ bfc,
                          float* __restrict__ out) {
    __shared__ __align__(16) float ps[D];
    int g = blockIdx.x;
    int f = threadIdx.x;
    float c = (float)max(start[g + 1] - start[g], 1);
    ps[f] = sums[g * D + f] / c;
    __syncthreads();
    float acc = bfc[f];
    #pragma unroll
    for (int k = 0; k < D; k += 4) {
        float4 pv = *(const float4*)&ps[k];
        acc += pv.x * Wfc[k * D + f] + pv.y * Wfc[(k + 1) * D + f] +
               pv.z * Wfc[(k + 2) * D + f] + pv.w * Wfc[(k + 3) * D + f];
    }
    out[g * D + f] = acc;
}

extern "C" void kernel_launch(void* const* d_in, const int* in_sizes, int n_in,
                              void* d_out, int out_size, void* d_ws, size_t ws_size,
                              hipStream_t stream) {
    const float* x   = (const float*)d_in[0];
    const int* ei    = (const int*)d_in[1];   // [2, E]
    const int* batch = (const int*)d_in[2];
    const float* W1  = (const float*)d_in[3];
    const float* b1  = (const float*)d_in[4];
    const float* W2  = (const float*)d_in[5];
    const float* b2  = (const float*)d_in[6];
    const float* Wfc = (const float*)d_in[7];
    const float* bfc = (const float*)d_in[8];
    float* out = (float*)d_out;

    const int* src = ei;
    const int* dst = ei + N_EDGES;

    // workspace layout
    unsigned char* Hq    = (unsigned char*)d_ws;                 // N*D fp8
    unsigned short* G    = (unsigned short*)(Hq + (size_t)N_NODES * D);  // N*D bf16
    int2* pairs          = (int2*)(G + (size_t)N_NODES * D);     // E
    float* dinv          = (float*)(pairs + N_EDGES);            // N
    int*   deg           = (int*)(dinv + N_NODES);               // N
    int*   cursor        = deg + N_NODES;                        // N (contiguous with deg)
    int*   rs            = cursor + N_NODES;                     // N+4
    int*   bsum          = rs + N_NODES + 4;                     // 512
    int*   start         = bsum + 512;                           // NG+1 (+pad)
    float* sums          = (float*)(start + NG + 8);             // NG*D

    hipMemsetAsync(deg, 0, 2 * N_NODES * sizeof(int), stream);   // deg + cursor
    hipMemsetAsync(sums, 0, NG * D * sizeof(float), stream);

    // --- CSR build (shared by both layers) + graph bounds ---
    hist_kernel<<<(N_EDGES + 255) / 256, 256, 0, stream>>>(dst, deg);
    scan1_kernel<<<SCAN_NB, 256, 0, stream>>>(deg, rs, bsum, dinv);
    scan2_kernel<<<1, 512, 0, stream>>>(bsum);
    scan3_kernel<<<SCAN_NB, 256, 0, stream>>>(rs, bsum);
    fill_kernel<<<(N_EDGES + 255) / 256, 256, 0, stream>>>(src, dst, dinv, rs, cursor, pairs);
    bounds_kernel<<<1, 128, 0, stream>>>(batch, start);

    // --- layer 1 ---
    xw_mfma_kernel<true><<<512, 512, 0, stream>>>(x, W1, Hq);
    gather_kernel<<<(N_NODES + 3) / 4, 256, 0, stream>>>(Hq, rs, pairs, dinv, b1, G);

    // --- layer 2 ---
    xw_mfma_kernel<false><<<512, 512, 0, stream>>>(G, W2, Hq);
    gather_kernel<<<(N_NODES + 3) / 4, 256, 0, stream>>>(Hq, rs, pairs, dinv, b2, G);

    // --- mean pool + FC ---
    pool_kernel<<<NG * 16, 256, 0, stream>>>(G, start, sums);
    fc_kernel<<<NG, 128, 0, stream>>>(sums, start, Wfc, bfc, out);
}

// Round 6
// 324.691 us; speedup vs baseline: 1.1545x; 1.1545x over previous
//
#include <hip/hip_runtime.h>
#include <hip/hip_bf16.h>

#define N_NODES 100000
#define N_EDGES 800000
#define D 128
#define NG 64
#define SCAN_NB ((N_NODES + 255) / 256)   // 391
#define NTILES ((N_NODES + 63) / 64)      // 1563

typedef __attribute__((ext_vector_type(8))) short short8;
typedef __attribute__((ext_vector_type(4))) float f32x4;
typedef __attribute__((ext_vector_type(2))) float f32x2;

static __device__ __forceinline__ unsigned short f2bf(float f) {
    unsigned u = __float_as_uint(f);
    unsigned r = (u + 0x7FFF + ((u >> 16) & 1)) >> 16;   // RTN-even
    return (unsigned short)r;
}
static __device__ __forceinline__ float bf2f(unsigned short b) {
    return __uint_as_float((unsigned)b << 16);
}
static __device__ __forceinline__ unsigned char f2fp8(float v) {
    int p = __builtin_amdgcn_cvt_pk_fp8_f32(v, v, 0, false);  // RNE, OCP e4m3fn
    return (unsigned char)(p & 0xFF);
}

// ---------------- CSR build: histogram / scan(+dinv) / fill ----------------

__global__ void hist_kernel(const int* __restrict__ dst, int* __restrict__ deg) {
    int e = blockIdx.x * blockDim.x + threadIdx.x;
    if (e < N_EDGES) atomicAdd(&deg[dst[e]], 1);
}

__global__ __launch_bounds__(256) void scan1_kernel(const int* __restrict__ deg,
                                                    int* __restrict__ rs,
                                                    int* __restrict__ bsum,
                                                    float* __restrict__ dinv) {
    __shared__ int wsum[4];
    int i = blockIdx.x * 256 + threadIdx.x;
    int lane = threadIdx.x & 63;
    int wid = threadIdx.x >> 6;
    int v = (i < N_NODES) ? deg[i] : 0;
    if (i < N_NODES) dinv[i] = rsqrtf((float)v + 1.0f);  // +1 self loop
    int x = v;
    #pragma unroll
    for (int off = 1; off < 64; off <<= 1) {
        int y = __shfl_up(x, off);
        if (lane >= off) x += y;
    }
    if (lane == 63) wsum[wid] = x;
    __syncthreads();
    int add = 0;
    #pragma unroll
    for (int w = 0; w < 3; ++w) if (w < wid) add += wsum[w];
    int incl = x + add;
    if (i < N_NODES) rs[i] = incl - v;
    if (threadIdx.x == 255) bsum[blockIdx.x] = incl;
}

__global__ __launch_bounds__(512) void scan2_kernel(int* __restrict__ bsum) {
    __shared__ int s[512];
    int t = threadIdx.x;
    int v = (t < SCAN_NB) ? bsum[t] : 0;
    s[t] = v;
    __syncthreads();
    for (int off = 1; off < 512; off <<= 1) {
        int y = (t >= off) ? s[t - off] : 0;
        __syncthreads();
        s[t] += y;
        __syncthreads();
    }
    if (t < SCAN_NB) bsum[t] = s[t] - v;
}

__global__ void scan3_kernel(int* __restrict__ rs, const int* __restrict__ bsum) {
    int i = blockIdx.x * blockDim.x + threadIdx.x;
    if (i < N_NODES) rs[i] += bsum[i >> 8];
    if (i == 0) rs[N_NODES] = N_EDGES;
}

__global__ void fill_kernel(const int* __restrict__ src, const int* __restrict__ dst,
                            const float* __restrict__ dinv, const int* __restrict__ rs,
                            int* __restrict__ cursor, int2* __restrict__ pairs) {
    int e = blockIdx.x * blockDim.x + threadIdx.x;
    if (e < N_EDGES) {
        int d = dst[e];
        int s = src[e];
        int p = rs[d] + atomicAdd(&cursor[d], 1);
        pairs[p] = make_int2(s, __float_as_int(dinv[s] * dinv[d]));
    }
}

// ---------------- graph boundaries from sorted batch ----------------

__global__ void bounds_kernel(const int* __restrict__ batch, int* __restrict__ start) {
    int g = threadIdx.x;
    if (g > NG) return;
    if (g == NG) { start[NG] = N_NODES; return; }
    int lo = 0, hi = N_NODES;
    while (lo < hi) {
        int mid = (lo + hi) >> 1;
        if (batch[mid] < g) lo = mid + 1; else hi = mid;
    }
    start[g] = lo;
}

// ---------------- dense transform via MFMA: Hq = fp8( A @ (Whi+Wlo) ) ------

template <bool IN_F32>
__global__ __launch_bounds__(512) void xw_mfma_kernel(const void* __restrict__ Xin,
                                                      const float* __restrict__ W,
                                                      unsigned char* __restrict__ Hq) {
    __shared__ __align__(16) unsigned short bt_hi[128 * 128];  // 32 KB, Bt[n][k]
    __shared__ __align__(16) unsigned short bt_lo[128 * 128];  // 32 KB
    __shared__ __align__(16) unsigned short atile[64 * 128];   // 16 KB, A[row][k]

    const int t = threadIdx.x;
    const int lane = t & 63;
    const int wid = t >> 6;

    #pragma unroll 4
    for (int i = 0; i < 32; ++i) {
        int idx = t + i * 512;
        int k = idx >> 7;
        int n = idx & 127;
        float w = W[idx];
        unsigned short hi = f2bf(w);
        unsigned short lo = f2bf(w - bf2f(hi));
        int byte = (n * 256 + k * 2) ^ ((n & 7) << 4);
        *(unsigned short*)((char*)bt_hi + byte) = hi;
        *(unsigned short*)((char*)bt_lo + byte) = lo;
    }

    const int mrow = (wid >> 1) * 16;
    const int ncol = (wid & 1) * 64;
    const int ar = mrow + (lane & 15);
    const int ak = (lane >> 4) * 8;

    for (int tile = blockIdx.x; tile < NTILES; tile += gridDim.x) {
        const int node0 = tile * 64;
        __syncthreads();

        #pragma unroll
        for (int p = 0; p < 2; ++p) {
            int j = t + p * 512;
            int row = j >> 4;
            int c8 = (j & 15) * 8;
            int node = node0 + row;
            short8 v = 0;
            if (IN_F32) {
                const float* X = (const float*)Xin;
                if (node < N_NODES) {
                    const float* xr = &X[(size_t)node * 128 + c8];
                    float4 a = *(const float4*)xr;
                    float4 b = *(const float4*)(xr + 4);
                    v[0] = (short)f2bf(a.x); v[1] = (short)f2bf(a.y);
                    v[2] = (short)f2bf(a.z); v[3] = (short)f2bf(a.w);
                    v[4] = (short)f2bf(b.x); v[5] = (short)f2bf(b.y);
                    v[6] = (short)f2bf(b.z); v[7] = (short)f2bf(b.w);
                }
            } else {
                const unsigned short* X = (const unsigned short*)Xin;
                if (node < N_NODES) v = *(const short8*)&X[(size_t)node * 128 + c8];
            }
            int byte = (row * 256 + c8 * 2) ^ ((row & 7) << 4);
            *(short8*)((char*)atile + byte) = v;
        }
        __syncthreads();

        f32x4 acc[4];
        #pragma unroll
        for (int nt = 0; nt < 4; ++nt) acc[nt] = 0.f;

        #pragma unroll
        for (int kc = 0; kc < 128; kc += 32) {
            short8 a = *(const short8*)((const char*)atile +
                        ((ar * 256 + (kc + ak) * 2) ^ ((ar & 7) << 4)));
            #pragma unroll
            for (int nt = 0; nt < 4; ++nt) {
                int col = ncol + nt * 16 + (lane & 15);
                int boff = (col * 256 + (kc + ak) * 2) ^ ((col & 7) << 4);
                short8 bh = *(const short8*)((const char*)bt_hi + boff);
                acc[nt] = __builtin_amdgcn_mfma_f32_16x16x32_bf16(a, bh, acc[nt], 0, 0, 0);
                short8 bl = *(const short8*)((const char*)bt_lo + boff);
                acc[nt] = __builtin_amdgcn_mfma_f32_16x16x32_bf16(a, bl, acc[nt], 0, 0, 0);
            }
        }

        // ---- store C as fp8 (byte stores) ----
        #pragma unroll
        for (int nt = 0; nt < 4; ++nt) {
            #pragma unroll
            for (int r = 0; r < 4; ++r) {
                int node = node0 + mrow + (lane >> 4) * 4 + r;
                if (node < N_NODES)
                    Hq[(size_t)node * 128 + ncol + nt * 16 + (lane & 15)] = f2fp8(acc[nt][r]);
            }
        }
    }
}

// ---------------- CSR gather (fp8 in, bf16 out) + fused epilogue -----------
// wave per node; 4 edges per load instruction: group g = lane>>4 handles
// edge i+g, lane covers feature chunk fl = lane&15 (8 fp8 = 8 B).
// Cross-group combine: shfl_xor masks 16, 32. Lanes 0-15 write the row.

__global__ __launch_bounds__(256) void gather_kernel(const unsigned char* __restrict__ Hq,
                                                     const int* __restrict__ rs,
                                                     const int2* __restrict__ pairs,
                                                     const float* __restrict__ dinv,
                                                     const float* __restrict__ bias,
                                                     unsigned short* __restrict__ out) {
    int node = blockIdx.x * 4 + (threadIdx.x >> 6);
    if (node >= N_NODES) return;
    int lane = threadIdx.x & 63;
    int g = lane >> 4;
    int fl = lane & 15;

    float di = dinv[node];
    float wself = (g == 0) ? di * di : 0.f;

    float acc[8];
    {
        uint2 sv = *(const uint2*)&Hq[(size_t)node * 128 + fl * 8];
        f32x2 a0 = __builtin_amdgcn_cvt_pk_f32_fp8((int)sv.x, false);
        f32x2 a1 = __builtin_amdgcn_cvt_pk_f32_fp8((int)sv.x, true);
        f32x2 a2 = __builtin_amdgcn_cvt_pk_f32_fp8((int)sv.y, false);
        f32x2 a3 = __builtin_amdgcn_cvt_pk_f32_fp8((int)sv.y, true);
        acc[0] = a0[0] * wself; acc[1] = a0[1] * wself;
        acc[2] = a1[0] * wself; acc[3] = a1[1] * wself;
        acc[4] = a2[0] * wself; acc[5] = a2[1] * wself;
        acc[6] = a3[0] * wself; acc[7] = a3[1] * wself;
    }

    int beg = rs[node];
    int end = rs[node + 1];
    int last = end - 1;
    for (int i = beg; i < end; i += 4) {
        int idx = i + g;
        int2 p = pairs[min(idx, last)];
        float w = (idx < end) ? __int_as_float(p.y) : 0.f;
        uint2 hv = *(const uint2*)&Hq[(size_t)p.x * 128 + fl * 8];
        f32x2 h0 = __builtin_amdgcn_cvt_pk_f32_fp8((int)hv.x, false);
        f32x2 h1 = __builtin_amdgcn_cvt_pk_f32_fp8((int)hv.x, true);
        f32x2 h2 = __builtin_amdgcn_cvt_pk_f32_fp8((int)hv.y, false);
        f32x2 h3 = __builtin_amdgcn_cvt_pk_f32_fp8((int)hv.y, true);
        acc[0] = fmaf(h0[0], w, acc[0]); acc[1] = fmaf(h0[1], w, acc[1]);
        acc[2] = fmaf(h1[0], w, acc[2]); acc[3] = fmaf(h1[1], w, acc[3]);
        acc[4] = fmaf(h2[0], w, acc[4]); acc[5] = fmaf(h2[1], w, acc[5]);
        acc[6] = fmaf(h3[0], w, acc[6]); acc[7] = fmaf(h3[1], w, acc[7]);
    }

    // combine the 4 edge-groups (lanes l, l+16, l+32, l+48)
    #pragma unroll
    for (int mask = 16; mask <= 32; mask <<= 1) {
        #pragma unroll
        for (int j = 0; j < 8; ++j) acc[j] += __shfl_xor(acc[j], mask);
    }

    if (g == 0) {
        float4 bb0 = *(const float4*)&bias[fl * 8];
        float4 bb1 = *(const float4*)&bias[fl * 8 + 4];
        short8 o;
        o[0] = (short)f2bf(fmaxf(acc[0] + bb0.x, 0.f));
        o[1] = (short)f2bf(fmaxf(acc[1] + bb0.y, 0.f));
        o[2] = (short)f2bf(fmaxf(acc[2] + bb0.z, 0.f));
        o[3] = (short)f2bf(fmaxf(acc[3] + bb0.w, 0.f));
        o[4] = (short)f2bf(fmaxf(acc[4] + bb1.x, 0.f));
        o[5] = (short)f2bf(fmaxf(acc[5] + bb1.y, 0.f));
        o[6] = (short)f2bf(fmaxf(acc[6] + bb1.z, 0.f));
        o[7] = (short)f2bf(fmaxf(acc[7] + bb1.w, 0.f));
        *(short8*)&out[(size_t)node * 128 + fl * 8] = o;
    }
}

// ---------------- mean pool: dense segmented sum over start[] --------------

__global__ __launch_bounds__(256) void pool_kernel(const unsigned short* __restrict__ G,
                                                   const int* __restrict__ start,
                                                   float* __restrict__ sums) {
    __shared__ float red[16][132];
    int g = blockIdx.x >> 4;
    int s = blockIdx.x & 15;
    int n0 = start[g], n1 = start[g + 1];
    int slot = threadIdx.x & 15;
    int nl = threadIdx.x >> 4;

    float acc[8];
    #pragma unroll
    for (int j = 0; j < 8; ++j) acc[j] = 0.f;

    for (int node = n0 + s * 16 + nl; node < n1; node += 256) {
        short8 v = *(const short8*)&G[(size_t)node * 128 + slot * 8];
        #pragma unroll
        for (int j = 0; j < 8; ++j) acc[j] += bf2f((unsigned short)v[j]);
    }

    #pragma unroll
    for (int j = 0; j < 8; ++j) red[nl][slot * 8 + j] = acc[j];
    __syncthreads();
    #pragma unroll
    for (int off = 8; off > 0; off >>= 1) {
        if (nl < off) {
            #pragma unroll
            for (int j = 0; j < 8; ++j)
                red[nl][slot * 8 + j] += red[nl + off][slot * 8 + j];
        }
        __syncthreads();
    }
    if (nl == 0) {
        #pragma unroll
        for (int j = 0; j < 8; ++j)
            unsafeAtomicAdd(&sums[g * D + slot * 8 + j], red[0][slot * 8 + j]);
    }
}

// ---------------- final FC ----------------

__global__ void fc_kernel(const float* __restrict__ sums, const int* __restrict__ start,
                          const float* __restrict__ Wfc, const float* __restrict__ bfc,
                          float* __restrict__ out) {
    __shared__ __align__(16) float ps[D];
    int g = blockIdx.x;
    int f = threadIdx.x;
    float c = (float)max(start[g + 1] - start[g], 1);
    ps[f] = sums[g * D + f] / c;
    __syncthreads();
    float acc = bfc[f];
    #pragma unroll
    for (int k = 0; k < D; k += 4) {
        float4 pv = *(const float4*)&ps[k];
        acc += pv.x * Wfc[k * D + f] + pv.y * Wfc[(k + 1) * D + f] +
               pv.z * Wfc[(k + 2) * D + f] + pv.w * Wfc[(k + 3) * D + f];
    }
    out[g * D + f] = acc;
}

extern "C" void kernel_launch(void* const* d_in, const int* in_sizes, int n_in,
                              void* d_out, int out_size, void* d_ws, size_t ws_size,
                              hipStream_t stream) {
    const float* x   = (const float*)d_in[0];
    const int* ei    = (const int*)d_in[1];   // [2, E]
    const int* batch = (const int*)d_in[2];
    const float* W1  = (const float*)d_in[3];
    const float* b1  = (const float*)d_in[4];
    const float* W2  = (const float*)d_in[5];
    const float* b2  = (const float*)d_in[6];
    const float* Wfc = (const float*)d_in[7];
    const float* bfc = (const float*)d_in[8];
    float* out = (float*)d_out;

    const int* src = ei;
    const int* dst = ei + N_EDGES;

    // workspace layout
    unsigned char* Hq    = (unsigned char*)d_ws;                 // N*D fp8
    unsigned short* G    = (unsigned short*)(Hq + (size_t)N_NODES * D);  // N*D bf16
    int2* pairs          = (int2*)(G + (size_t)N_NODES * D);     // E
    float* dinv          = (float*)(pairs + N_EDGES);            // N
    int*   deg           = (int*)(dinv + N_NODES);               // N
    int*   cursor        = deg + N_NODES;                        // N (contiguous with deg)
    int*   rs            = cursor + N_NODES;                     // N+4
    int*   bsum          = rs + N_NODES + 4;                     // 512
    int*   start         = bsum + 512;                           // NG+1 (+pad)
    float* sums          = (float*)(start + NG + 8);             // NG*D

    hipMemsetAsync(deg, 0, 2 * N_NODES * sizeof(int), stream);   // deg + cursor
    hipMemsetAsync(sums, 0, NG * D * sizeof(float), stream);

    // --- CSR build (shared by both layers) + graph bounds ---
    hist_kernel<<<(N_EDGES + 255) / 256, 256, 0, stream>>>(dst, deg);
    scan1_kernel<<<SCAN_NB, 256, 0, stream>>>(deg, rs, bsum, dinv);
    scan2_kernel<<<1, 512, 0, stream>>>(bsum);
    scan3_kernel<<<SCAN_NB, 256, 0, stream>>>(rs, bsum);
    fill_kernel<<<(N_EDGES + 255) / 256, 256, 0, stream>>>(src, dst, dinv, rs, cursor, pairs);
    bounds_kernel<<<1, 128, 0, stream>>>(batch, start);

    // --- layer 1 ---
    xw_mfma_kernel<true><<<512, 512, 0, stream>>>(x, W1, Hq);
    gather_kernel<<<(N_NODES + 3) / 4, 256, 0, stream>>>(Hq, rs, pairs, dinv, b1, G);

    // --- layer 2 ---
    xw_mfma_kernel<false><<<512, 512, 0, stream>>>(G, W2, Hq);
    gather_kernel<<<(N_NODES + 3) / 4, 256, 0, stream>>>(Hq, rs, pairs, dinv, b2, G);

    // --- mean pool + FC ---
    pool_kernel<<<NG * 16, 256, 0, stream>>>(G, start, sums);
    fc_kernel<<<NG, 128, 0, stream>>>(sums, start, Wfc, bfc, out);
}

// Round 7
// 305.709 us; speedup vs baseline: 1.2262x; 1.0621x over previous
//
#include <hip/hip_runtime.h>
#include <hip/hip_bf16.h>

#define N_NODES 100000
#define N_EDGES 800000
#define D 128
#define NG 64
#define SCAN_NB ((N_NODES + 255) / 256)   // 391
#define NTILES ((N_NODES + 63) / 64)      // 1563

typedef __attribute__((ext_vector_type(8))) short short8;
typedef __attribute__((ext_vector_type(4))) float f32x4;
typedef __attribute__((ext_vector_type(2))) float f32x2;

static __device__ __forceinline__ unsigned short f2bf(float f) {
    unsigned u = __float_as_uint(f);
    unsigned r = (u + 0x7FFF + ((u >> 16) & 1)) >> 16;   // RTN-even
    return (unsigned short)r;
}
static __device__ __forceinline__ float bf2f(unsigned short b) {
    return __uint_as_float((unsigned)b << 16);
}
static __device__ __forceinline__ unsigned char f2fp8(float v) {
    int p = __builtin_amdgcn_cvt_pk_fp8_f32(v, v, 0, false);  // RNE, OCP e4m3fn
    return (unsigned char)(p & 0xFF);
}

// ---------------- CSR build: histogram / scan(+dinv) / fill ----------------

__global__ void hist_kernel(const int* __restrict__ dst, int* __restrict__ deg) {
    int e = blockIdx.x * blockDim.x + threadIdx.x;
    if (e < N_EDGES) atomicAdd(&deg[dst[e]], 1);
}

__global__ __launch_bounds__(256) void scan1_kernel(const int* __restrict__ deg,
                                                    int* __restrict__ rs,
                                                    int* __restrict__ bsum,
                                                    float* __restrict__ dinv) {
    __shared__ int wsum[4];
    int i = blockIdx.x * 256 + threadIdx.x;
    int lane = threadIdx.x & 63;
    int wid = threadIdx.x >> 6;
    int v = (i < N_NODES) ? deg[i] : 0;
    if (i < N_NODES) dinv[i] = rsqrtf((float)v + 1.0f);  // +1 self loop
    int x = v;
    #pragma unroll
    for (int off = 1; off < 64; off <<= 1) {
        int y = __shfl_up(x, off);
        if (lane >= off) x += y;
    }
    if (lane == 63) wsum[wid] = x;
    __syncthreads();
    int add = 0;
    #pragma unroll
    for (int w = 0; w < 3; ++w) if (w < wid) add += wsum[w];
    int incl = x + add;
    if (i < N_NODES) rs[i] = incl - v;
    if (threadIdx.x == 255) bsum[blockIdx.x] = incl;
}

__global__ __launch_bounds__(512) void scan2_kernel(int* __restrict__ bsum) {
    __shared__ int s[512];
    int t = threadIdx.x;
    int v = (t < SCAN_NB) ? bsum[t] : 0;
    s[t] = v;
    __syncthreads();
    for (int off = 1; off < 512; off <<= 1) {
        int y = (t >= off) ? s[t - off] : 0;
        __syncthreads();
        s[t] += y;
        __syncthreads();
    }
    if (t < SCAN_NB) bsum[t] = s[t] - v;
}

__global__ void scan3_kernel(int* __restrict__ rs, const int* __restrict__ bsum) {
    int i = blockIdx.x * blockDim.x + threadIdx.x;
    if (i < N_NODES) rs[i] += bsum[i >> 8];
    if (i == 0) rs[N_NODES] = N_EDGES;
}

__global__ void fill_kernel(const int* __restrict__ src, const int* __restrict__ dst,
                            const float* __restrict__ dinv, const int* __restrict__ rs,
                            int* __restrict__ cursor, int2* __restrict__ pairs) {
    int e = blockIdx.x * blockDim.x + threadIdx.x;
    if (e < N_EDGES) {
        int d = dst[e];
        int s = src[e];
        int p = rs[d] + atomicAdd(&cursor[d], 1);
        pairs[p] = make_int2(s, __float_as_int(dinv[s] * dinv[d]));
    }
}

// ---------------- graph boundaries from sorted batch ----------------

__global__ void bounds_kernel(const int* __restrict__ batch, int* __restrict__ start) {
    int g = threadIdx.x;
    if (g > NG) return;
    if (g == NG) { start[NG] = N_NODES; return; }
    int lo = 0, hi = N_NODES;
    while (lo < hi) {
        int mid = (lo + hi) >> 1;
        if (batch[mid] < g) lo = mid + 1; else hi = mid;
    }
    start[g] = lo;
}

// ---------------- dense transform via MFMA: Hq = fp8( A @ (Whi+Wlo) ) ------

template <bool IN_F32>
__global__ __launch_bounds__(512) void xw_mfma_kernel(const void* __restrict__ Xin,
                                                      const float* __restrict__ W,
                                                      unsigned char* __restrict__ Hq) {
    __shared__ __align__(16) unsigned short bt_hi[128 * 128];  // 32 KB, Bt[n][k]
    __shared__ __align__(16) unsigned short bt_lo[128 * 128];  // 32 KB
    __shared__ __align__(16) unsigned short atile[64 * 128];   // 16 KB, A[row][k]

    const int t = threadIdx.x;
    const int lane = t & 63;
    const int wid = t >> 6;

    #pragma unroll 4
    for (int i = 0; i < 32; ++i) {
        int idx = t + i * 512;
        int k = idx >> 7;
        int n = idx & 127;
        float w = W[idx];
        unsigned short hi = f2bf(w);
        unsigned short lo = f2bf(w - bf2f(hi));
        int byte = (n * 256 + k * 2) ^ ((n & 7) << 4);
        *(unsigned short*)((char*)bt_hi + byte) = hi;
        *(unsigned short*)((char*)bt_lo + byte) = lo;
    }

    const int mrow = (wid >> 1) * 16;
    const int ncol = (wid & 1) * 64;
    const int ar = mrow + (lane & 15);
    const int ak = (lane >> 4) * 8;

    for (int tile = blockIdx.x; tile < NTILES; tile += gridDim.x) {
        const int node0 = tile * 64;
        __syncthreads();

        #pragma unroll
        for (int p = 0; p < 2; ++p) {
            int j = t + p * 512;
            int row = j >> 4;
            int c8 = (j & 15) * 8;
            int node = node0 + row;
            short8 v = 0;
            if (IN_F32) {
                const float* X = (const float*)Xin;
                if (node < N_NODES) {
                    const float* xr = &X[(size_t)node * 128 + c8];
                    float4 a = *(const float4*)xr;
                    float4 b = *(const float4*)(xr + 4);
                    v[0] = (short)f2bf(a.x); v[1] = (short)f2bf(a.y);
                    v[2] = (short)f2bf(a.z); v[3] = (short)f2bf(a.w);
                    v[4] = (short)f2bf(b.x); v[5] = (short)f2bf(b.y);
                    v[6] = (short)f2bf(b.z); v[7] = (short)f2bf(b.w);
                }
            } else {
                const unsigned short* X = (const unsigned short*)Xin;
                if (node < N_NODES) v = *(const short8*)&X[(size_t)node * 128 + c8];
            }
            int byte = (row * 256 + c8 * 2) ^ ((row & 7) << 4);
            *(short8*)((char*)atile + byte) = v;
        }
        __syncthreads();

        f32x4 acc[4];
        #pragma unroll
        for (int nt = 0; nt < 4; ++nt) acc[nt] = 0.f;

        #pragma unroll
        for (int kc = 0; kc < 128; kc += 32) {
            short8 a = *(const short8*)((const char*)atile +
                        ((ar * 256 + (kc + ak) * 2) ^ ((ar & 7) << 4)));
            #pragma unroll
            for (int nt = 0; nt < 4; ++nt) {
                int col = ncol + nt * 16 + (lane & 15);
                int boff = (col * 256 + (kc + ak) * 2) ^ ((col & 7) << 4);
                short8 bh = *(const short8*)((const char*)bt_hi + boff);
                acc[nt] = __builtin_amdgcn_mfma_f32_16x16x32_bf16(a, bh, acc[nt], 0, 0, 0);
                short8 bl = *(const short8*)((const char*)bt_lo + boff);
                acc[nt] = __builtin_amdgcn_mfma_f32_16x16x32_bf16(a, bl, acc[nt], 0, 0, 0);
            }
        }

        // ---- store C as fp8 (byte stores) ----
        #pragma unroll
        for (int nt = 0; nt < 4; ++nt) {
            #pragma unroll
            for (int r = 0; r < 4; ++r) {
                int node = node0 + mrow + (lane >> 4) * 4 + r;
                if (node < N_NODES)
                    Hq[(size_t)node * 128 + ncol + nt * 16 + (lane & 15)] = f2fp8(acc[nt][r]);
            }
        }
    }
}

// ---------------- CSR gather (fp8 in, bf16 out) + fused epilogue -----------
// wave per node; group g = lane>>4 handles edges j = 4t+g, lane covers
// feature chunk fl = lane&15 (8 fp8 = 8 B). The per-node edge metadata is
// fetched with ONE coalesced load (pairs[beg+lane]), redistributed via
// register shfl, so the up-to-4 H-row gathers issue back-to-back with no
// dependent-load chain. deg>16 falls to a (rare) serial loop.

#define ACC8(HV, W)                                                        \
    {                                                                      \
        f32x2 _h0 = __builtin_amdgcn_cvt_pk_f32_fp8((int)(HV).x, false);   \
        f32x2 _h1 = __builtin_amdgcn_cvt_pk_f32_fp8((int)(HV).x, true);    \
        f32x2 _h2 = __builtin_amdgcn_cvt_pk_f32_fp8((int)(HV).y, false);   \
        f32x2 _h3 = __builtin_amdgcn_cvt_pk_f32_fp8((int)(HV).y, true);    \
        acc[0] = fmaf(_h0[0], (W), acc[0]); acc[1] = fmaf(_h0[1], (W), acc[1]); \
        acc[2] = fmaf(_h1[0], (W), acc[2]); acc[3] = fmaf(_h1[1], (W), acc[3]); \
        acc[4] = fmaf(_h2[0], (W), acc[4]); acc[5] = fmaf(_h2[1], (W), acc[5]); \
        acc[6] = fmaf(_h3[0], (W), acc[6]); acc[7] = fmaf(_h3[1], (W), acc[7]); \
    }

__global__ __launch_bounds__(256) void gather_kernel(const unsigned char* __restrict__ Hq,
                                                     const int* __restrict__ rs,
                                                     const int2* __restrict__ pairs,
                                                     const float* __restrict__ dinv,
                                                     const float* __restrict__ bias,
                                                     unsigned short* __restrict__ out) {
    int node = blockIdx.x * 4 + (threadIdx.x >> 6);
    if (node >= N_NODES) return;
    const int lane = threadIdx.x & 63;
    const int g = lane >> 4;
    const int fl = lane & 15;

    int beg = rs[node];
    int end = rs[node + 1];
    int deg = end - beg;

    float di = dinv[node];
    float wself = (g == 0) ? di * di : 0.f;

    float acc[8];
    {
        uint2 sv = *(const uint2*)&Hq[(size_t)node * 128 + fl * 8];
        f32x2 a0 = __builtin_amdgcn_cvt_pk_f32_fp8((int)sv.x, false);
        f32x2 a1 = __builtin_amdgcn_cvt_pk_f32_fp8((int)sv.x, true);
        f32x2 a2 = __builtin_amdgcn_cvt_pk_f32_fp8((int)sv.y, false);
        f32x2 a3 = __builtin_amdgcn_cvt_pk_f32_fp8((int)sv.y, true);
        acc[0] = a0[0] * wself; acc[1] = a0[1] * wself;
        acc[2] = a1[0] * wself; acc[3] = a1[1] * wself;
        acc[4] = a2[0] * wself; acc[5] = a2[1] * wself;
        acc[6] = a3[0] * wself; acc[7] = a3[1] * wself;
    }

    if (deg > 0) {
        // one coalesced metadata load covers the first min(deg,64) edges
        int2 pall = pairs[beg + min(lane, deg - 1)];
        int niter = (deg + 3) >> 2;          // wave-uniform

        const int j0 = g, j1 = g + 4, j2 = g + 8, j3 = g + 12;
        int s0 = __shfl(pall.x, j0), s1 = __shfl(pall.x, j1);
        int s2 = __shfl(pall.x, j2), s3 = __shfl(pall.x, j3);
        float w0 = (j0 < deg) ? __int_as_float(__shfl(pall.y, j0)) : 0.f;
        float w1 = (j1 < deg) ? __int_as_float(__shfl(pall.y, j1)) : 0.f;
        float w2 = (j2 < deg) ? __int_as_float(__shfl(pall.y, j2)) : 0.f;
        float w3 = (j3 < deg) ? __int_as_float(__shfl(pall.y, j3)) : 0.f;

        uint2 h0 = make_uint2(0u, 0u), h1 = h0, h2 = h0, h3 = h0;
        h0 = *(const uint2*)&Hq[(size_t)s0 * 128 + fl * 8];   // niter >= 1
        if (niter > 1) h1 = *(const uint2*)&Hq[(size_t)s1 * 128 + fl * 8];
        if (niter > 2) h2 = *(const uint2*)&Hq[(size_t)s2 * 128 + fl * 8];
        if (niter > 3) h3 = *(const uint2*)&Hq[(size_t)s3 * 128 + fl * 8];

        ACC8(h0, w0);
        ACC8(h1, w1);
        ACC8(h2, w2);
        ACC8(h3, w3);

        if (deg > 16) {                      // rare (Poisson(8): ~0.4%)
            for (int j = 16 + g; j < deg; j += 4) {
                int2 p = pairs[beg + j];
                float w = __int_as_float(p.y);
                uint2 hv = *(const uint2*)&Hq[(size_t)p.x * 128 + fl * 8];
                ACC8(hv, w);
            }
        }
    }

    // combine the 4 edge-groups (lanes l, l+16, l+32, l+48)
    #pragma unroll
    for (int mask = 16; mask <= 32; mask <<= 1) {
        #pragma unroll
        for (int j = 0; j < 8; ++j) acc[j] += __shfl_xor(acc[j], mask);
    }

    if (g == 0) {
        float4 bb0 = *(const float4*)&bias[fl * 8];
        float4 bb1 = *(const float4*)&bias[fl * 8 + 4];
        short8 o;
        o[0] = (short)f2bf(fmaxf(acc[0] + bb0.x, 0.f));
        o[1] = (short)f2bf(fmaxf(acc[1] + bb0.y, 0.f));
        o[2] = (short)f2bf(fmaxf(acc[2] + bb0.z, 0.f));
        o[3] = (short)f2bf(fmaxf(acc[3] + bb0.w, 0.f));
        o[4] = (short)f2bf(fmaxf(acc[4] + bb1.x, 0.f));
        o[5] = (short)f2bf(fmaxf(acc[5] + bb1.y, 0.f));
        o[6] = (short)f2bf(fmaxf(acc[6] + bb1.z, 0.f));
        o[7] = (short)f2bf(fmaxf(acc[7] + bb1.w, 0.f));
        *(short8*)&out[(size_t)node * 128 + fl * 8] = o;
    }
}

// ---------------- mean pool: dense segmented sum over start[] --------------

__global__ __launch_bounds__(256) void pool_kernel(const unsigned short* __restrict__ G,
                                                   const int* __restrict__ start,
                                                   float* __restrict__ sums) {
    __shared__ float red[16][132];
    int g = blockIdx.x >> 4;
    int s = blockIdx.x & 15;
    int n0 = start[g], n1 = start[g + 1];
    int slot = threadIdx.x & 15;
    int nl = threadIdx.x >> 4;

    float acc[8];
    #pragma unroll
    for (int j = 0; j < 8; ++j) acc[j] = 0.f;

    for (int node = n0 + s * 16 + nl; node < n1; node += 256) {
        short8 v = *(const short8*)&G[(size_t)node * 128 + slot * 8];
        #pragma unroll
        for (int j = 0; j < 8; ++j) acc[j] += bf2f((unsigned short)v[j]);
    }

    #pragma unroll
    for (int j = 0; j < 8; ++j) red[nl][slot * 8 + j] = acc[j];
    __syncthreads();
    #pragma unroll
    for (int off = 8; off > 0; off >>= 1) {
        if (nl < off) {
            #pragma unroll
            for (int j = 0; j < 8; ++j)
                red[nl][slot * 8 + j] += red[nl + off][slot * 8 + j];
        }
        __syncthreads();
    }
    if (nl == 0) {
        #pragma unroll
        for (int j = 0; j < 8; ++j)
            unsafeAtomicAdd(&sums[g * D + slot * 8 + j], red[0][slot * 8 + j]);
    }
}

// ---------------- final FC ----------------

__global__ void fc_kernel(const float* __restrict__ sums, const int* __restrict__ start,
                          const float* __restrict__ Wfc, const float* __restrict__ bfc,
                          float* __restrict__ out) {
    __shared__ __align__(16) float ps[D];
    int g = blockIdx.x;
    int f = threadIdx.x;
    float c = (float)max(start[g + 1] - start[g], 1);
    ps[f] = sums[g * D + f] / c;
    __syncthreads();
    float acc = bfc[f];
    #pragma unroll
    for (int k = 0; k < D; k += 4) {
        float4 pv = *(const float4*)&ps[k];
        acc += pv.x * Wfc[k * D + f] + pv.y * Wfc[(k + 1) * D + f] +
               pv.z * Wfc[(k + 2) * D + f] + pv.w * Wfc[(k + 3) * D + f];
    }
    out[g * D + f] = acc;
}

extern "C" void kernel_launch(void* const* d_in, const int* in_sizes, int n_in,
                              void* d_out, int out_size, void* d_ws, size_t ws_size,
                              hipStream_t stream) {
    const float* x   = (const float*)d_in[0];
    const int* ei    = (const int*)d_in[1];   // [2, E]
    const int* batch = (const int*)d_in[2];
    const float* W1  = (const float*)d_in[3];
    const float* b1  = (const float*)d_in[4];
    const float* W2  = (const float*)d_in[5];
    const float* b2  = (const float*)d_in[6];
    const float* Wfc = (const float*)d_in[7];
    const float* bfc = (const float*)d_in[8];
    float* out = (float*)d_out;

    const int* src = ei;
    const int* dst = ei + N_EDGES;

    // workspace layout
    unsigned char* Hq    = (unsigned char*)d_ws;                 // N*D fp8
    unsigned short* G    = (unsigned short*)(Hq + (size_t)N_NODES * D);  // N*D bf16
    int2* pairs          = (int2*)(G + (size_t)N_NODES * D);     // E
    float* dinv          = (float*)(pairs + N_EDGES);            // N
    int*   deg           = (int*)(dinv + N_NODES);               // N
    int*   cursor        = deg + N_NODES;                        // N (contiguous with deg)
    int*   rs            = cursor + N_NODES;                     // N+4
    int*   bsum          = rs + N_NODES + 4;                     // 512
    int*   start         = bsum + 512;                           // NG+1 (+pad)
    float* sums          = (float*)(start + NG + 8);             // NG*D

    hipMemsetAsync(deg, 0, 2 * N_NODES * sizeof(int), stream);   // deg + cursor
    hipMemsetAsync(sums, 0, NG * D * sizeof(float), stream);

    // --- CSR build (shared by both layers) + graph bounds ---
    hist_kernel<<<(N_EDGES + 255) / 256, 256, 0, stream>>>(dst, deg);
    scan1_kernel<<<SCAN_NB, 256, 0, stream>>>(deg, rs, bsum, dinv);
    scan2_kernel<<<1, 512, 0, stream>>>(bsum);
    scan3_kernel<<<SCAN_NB, 256, 0, stream>>>(rs, bsum);
    fill_kernel<<<(N_EDGES + 255) / 256, 256, 0, stream>>>(src, dst, dinv, rs, cursor, pairs);
    bounds_kernel<<<1, 128, 0, stream>>>(batch, start);

    // --- layer 1 ---
    xw_mfma_kernel<true><<<512, 512, 0, stream>>>(x, W1, Hq);
    gather_kernel<<<(N_NODES + 3) / 4, 256, 0, stream>>>(Hq, rs, pairs, dinv, b1, G);

    // --- layer 2 ---
    xw_mfma_kernel<false><<<512, 512, 0, stream>>>(G, W2, Hq);
    gather_kernel<<<(N_NODES + 3) / 4, 256, 0, stream>>>(Hq, rs, pairs, dinv, b2, G);

    // --- mean pool + FC ---
    pool_kernel<<<NG * 16, 256, 0, stream>>>(G, start, sums);
    fc_kernel<<<NG, 128, 0, stream>>>(sums, start, Wfc, bfc, out);
}